// Round 5
// baseline (54.949 us; speedup 1.0000x reference)
//
#include <hip/hip_runtime.h>
#include <hip/hip_bf16.h>

typedef float  f32x4  __attribute__((ext_vector_type(4)));
typedef float  f32x16 __attribute__((ext_vector_type(16)));
typedef short  s16x8  __attribute__((ext_vector_type(8)));
typedef unsigned int   u32x2 __attribute__((ext_vector_type(2)));
typedef unsigned int   u32x4 __attribute__((ext_vector_type(4)));

#define B_ 4
#define C_ 128
#define N_ 4096
#define NT 32            // 128-key supertiles
#define QSCALE 0.12751744f   // 1/sqrt(128) * log2(e)

typedef __attribute__((address_space(3))) unsigned int       lds_u32;
typedef __attribute__((address_space(1))) const unsigned int glb_u32;

// pack two f32 -> bf16x2 (round-half-up via +0x8000 + v_perm)
__device__ __forceinline__ unsigned int pkbf(float lo, float hi) {
    union { float f; unsigned int u; } a, b; a.f = lo; b.f = hi;
    return __builtin_amdgcn_perm(b.u + 0x8000u, a.u + 0x8000u, 0x07060302u);
}
// pack 4 f32 -> 4 fp8 e4m3 in one u32
__device__ __forceinline__ unsigned int pk_fp8x4(float a, float b, float c, float d) {
    int v = __builtin_amdgcn_cvt_pk_fp8_f32(a, b, 0, false);
    v = __builtin_amdgcn_cvt_pk_fp8_f32(c, d, v, true);
    return (unsigned int)v;
}
__device__ __forceinline__ s16x8 mk_frag(unsigned int a, unsigned int b,
                                         unsigned int c, unsigned int d) {
    union { u32x4 u; s16x8 v; } t; t.u = (u32x4){a, b, c, d}; return t.v;
}
__device__ __forceinline__ long mk64(unsigned int a, unsigned int b) {
    union { u32x2 u; long l; } t; t.u = (u32x2){a, b}; return t.l;
}
__device__ __forceinline__ f32x16 z16() {
    f32x16 v;
    #pragma unroll
    for (int r = 0; r < 16; r++) v[r] = 0.f;
    return v;
}
__device__ __forceinline__ void cp16(const unsigned char* g, unsigned char* l) {
    __builtin_amdgcn_global_load_lds((glb_u32*)g, (lds_u32*)l, 16, 0, 0);
}

// ---------------- W -> bf16 fragment-major (tiny, once) ----------------
__global__ __launch_bounds__(256) void wcvt_kernel(
    const float* __restrict__ wq, const float* __restrict__ wk,
    const float* __restrict__ wv, unsigned short* __restrict__ Wf)
{
    const int gid = blockIdx.x * 256 + threadIdx.x;   // 0..6143
    const int l = gid & 63, fid = gid >> 6;           // fid 0..95
    const int kc = fid & 7, ot = (fid >> 3) & 3, z = fid >> 5;
    const float* w = (z == 0) ? wq : (z == 1 ? wk : wv);
    const int o  = 32 * ot + (l & 31);
    const int c0 = 16 * kc + 8 * (l >> 5);
    const float* src = &w[o * C_ + c0];
    *(u32x4*)&Wf[fid * 512 + l * 8] = (u32x4){
        pkbf(src[0], src[1]), pkbf(src[2], src[3]),
        pkbf(src[4], src[5]), pkbf(src[6], src[7])};
}

// ---------------- projection: LDS-transposed X, bf16 MFMA, fp8 frag outputs ----
__global__ __launch_bounds__(256, 2) void proj_kernel(
    const float* __restrict__ x1, const float* __restrict__ x2,
    const float* __restrict__ bq, const float* __restrict__ bk,
    const float* __restrict__ bv,
    const unsigned short* __restrict__ Wf,
    unsigned char* __restrict__ Qf, unsigned char* __restrict__ Kf,
    unsigned char* __restrict__ Vf)
{
    __shared__ float Xs[2][C_ * 36];
    const int tid = threadIdx.x;
    const int ot  = tid >> 6;
    const int l = tid & 63, lo = l & 31, h = l >> 5;
    const int bid = blockIdx.x;
    const int b = bid & 3, tb = bid >> 2;
    const int n0 = tb * 32;

    { // coalesced f32x4 loads -> LDS [c][tok]
        const int q = tid & 7, c0 = tid >> 3;
        #pragma unroll
        for (int cc = 0; cc < 4; cc++) {
            const int c = c0 + 32 * cc;
            const size_t gof = ((size_t)b * C_ + c) * N_ + n0 + 4 * q;
            *(f32x4*)&Xs[0][c * 36 + 4 * q] = *(const f32x4*)&x1[gof];
            *(f32x4*)&Xs[1][c * 36 + 4 * q] = *(const f32x4*)&x2[gof];
        }
    }
    __syncthreads();

    auto ldW = [&](int z, int kc) -> s16x8 {
        return *(const s16x8*)&Wf[(((z * 4 + ot) * 8) + kc) * 512 + l * 8];
    };
    auto xfrag = [&](int z, int kc) -> s16x8 {
        const float* p = &Xs[z][(16 * kc + 8 * h) * 36 + lo];
        float f[8];
        #pragma unroll
        for (int i = 0; i < 8; i++) f[i] = p[i * 36];
        return mk_frag(pkbf(f[0], f[1]), pkbf(f[2], f[3]),
                       pkbf(f[4], f[5]), pkbf(f[6], f[7]));
    };

    f32x16 aq = z16(), ak = z16(), av = z16();
    s16x8 wqA = ldW(0, 0), wkA = ldW(1, 0), wvA = ldW(2, 0);
    s16x8 wqB, wkB, wvB;
    #pragma unroll
    for (int kc = 0; kc < 8; kc++) {
        if (kc & 1) {
            if (kc < 7) { wqA = ldW(0, kc + 1); wkA = ldW(1, kc + 1); wvA = ldW(2, kc + 1); }
            s16x8 f1 = xfrag(0, kc), f2 = xfrag(1, kc);
            aq = __builtin_amdgcn_mfma_f32_32x32x16_bf16(wqB, f1, aq, 0, 0, 0);
            ak = __builtin_amdgcn_mfma_f32_32x32x16_bf16(wkB, f2, ak, 0, 0, 0);
            av = __builtin_amdgcn_mfma_f32_32x32x16_bf16(f2, wvB, av, 0, 0, 0);
        } else {
            if (kc < 7) { wqB = ldW(0, kc + 1); wkB = ldW(1, kc + 1); wvB = ldW(2, kc + 1); }
            s16x8 f1 = xfrag(0, kc), f2 = xfrag(1, kc);
            aq = __builtin_amdgcn_mfma_f32_32x32x16_bf16(wqA, f1, aq, 0, 0, 0);
            ak = __builtin_amdgcn_mfma_f32_32x32x16_bf16(wkA, f2, ak, 0, 0, 0);
            av = __builtin_amdgcn_mfma_f32_32x32x16_bf16(f2, wvA, av, 0, 0, 0);
        }
    }

    const size_t fbase = (size_t)(b * 128 + tb) * 4096;
    auto slot_addr = [&](int rq) -> size_t {
        return fbase + (size_t)(2 * ot + (rq >> 1)) * 512 + (lo + 32 * (rq & 1)) * 8 + 4 * h;
    };
    #pragma unroll
    for (int rq = 0; rq < 4; rq++) {
        const int o0 = 32 * ot + 8 * rq + 4 * h;
        const f32x4 b4q = *(const f32x4*)&bq[o0];
        const f32x4 b4k = *(const f32x4*)&bk[o0];
        *(unsigned int*)&Qf[slot_addr(rq)] = pk_fp8x4(
            (aq[4*rq+0] + b4q[0]) * QSCALE, (aq[4*rq+1] + b4q[1]) * QSCALE,
            (aq[4*rq+2] + b4q[2]) * QSCALE, (aq[4*rq+3] + b4q[3]) * QSCALE);
        *(unsigned int*)&Kf[slot_addr(rq)] = pk_fp8x4(
            ak[4*rq+0] + b4k[0], ak[4*rq+1] + b4k[1],
            ak[4*rq+2] + b4k[2], ak[4*rq+3] + b4k[3]);
    }
    {
        const float bvv = bv[32 * ot + lo];
        #pragma unroll
        for (int rq = 0; rq < 4; rq++)
            *(unsigned int*)&Vf[slot_addr(rq)] = pk_fp8x4(
                av[4*rq+0] + bvv, av[4*rq+1] + bvv,
                av[4*rq+2] + bvv, av[4*rq+3] + bvv);
    }
}

// ---------------- attention: fp8, QK(t)/PV(t-1) pipelined, counted vmcnt ----
// 256 blocks x 512 thr; wave w: qi = w&1 (32-q tile), ks = w>>1 (32-key slice)
__global__ __launch_bounds__(512, 2) void attn_kernel(
    const unsigned char* __restrict__ Qf,
    const unsigned char* __restrict__ Kf,
    const unsigned char* __restrict__ Vf,
    const float* __restrict__ x1,
    float* __restrict__ out)
{
    __shared__ __align__(16) unsigned char smem[67584];
    __shared__ float Llds[4][32];

    const int tid = threadIdx.x;
    const int w  = tid >> 6;
    const int qi = w & 1, ks = w >> 1;
    const int l = tid & 63, lo = l & 31, h = l >> 5;
    const int bid = blockIdx.x;
    const int xcd = bid & 7, slot = bid >> 3;
    const int b  = xcd >> 1;
    const int qt = ((xcd & 1) << 5) | slot;     // 0..63
    const int q0 = qt * 64;

    const unsigned char* Kb = Kf + (size_t)b * 128 * 4096;
    const unsigned char* Vb = Vf + (size_t)b * 128 * 4096;

    long qf[8];
    {
        const unsigned char* qp = Qf + (size_t)(b * 128 + qt * 2 + qi) * 4096 + l * 8;
        #pragma unroll
        for (int cb = 0; cb < 8; cb++) qf[cb] = *(const long*)(qp + cb * 512);
    }

    f32x16 oacc[4];
    #pragma unroll
    for (int ct = 0; ct < 4; ct++) oacc[ct] = z16();
    float La = 0.f, Lb2 = 0.f;
    long vf[8];            // V frags of tile t (registers, consumed at t+1)
    long p0 = 0, p1 = 0;   // P frags of tile t

    auto stage = [&](int t, int buf) {
        const int tp = (t + slot) & 31;          // staggered sweep (L2 de-sync)
        const unsigned char* Ks = Kb + tp * 16384;
        const unsigned char* Vs = Vb + tp * 16384;
        unsigned char* db = smem + (buf << 15);
        cp16(Ks + (2*w)   * 1024 + l * 16, db + (2*w)   * 1024);
        cp16(Ks + (2*w+1) * 1024 + l * 16, db + (2*w+1) * 1024);
        cp16(Vs + (2*w)   * 1024 + l * 16, db + 16384 + (2*w)   * 1024);
        cp16(Vs + (2*w+1) * 1024 + l * 16, db + 16384 + (2*w+1) * 1024);
    };

    // QK of tile t interleaved with PV of tile t-1; softmax(t); V(t)->regs
    auto compute = [&](int t, int dopv) {
        const unsigned char* db  = smem + ((t & 1) << 15);
        const unsigned char* kb8 = db + ks * 4096;
        const unsigned char* vb8 = db + 16384 + ks * 4096;
        long kf[8];
        #pragma unroll
        for (int cb = 0; cb < 8; cb++) kf[cb] = *(const long*)(kb8 + cb * 512 + l * 8);
        f32x16 s = z16();
        __builtin_amdgcn_s_setprio(1);
        if (dopv) {
            #pragma unroll
            for (int cb = 0; cb < 8; cb++) {
                s = __builtin_amdgcn_mfma_f32_32x32x16_fp8_fp8(kf[cb], qf[cb], s, 0, 0, 0);
                const int ct = cb >> 1;
                oacc[ct] = __builtin_amdgcn_mfma_f32_32x32x16_fp8_fp8(
                    vf[cb], (cb & 1) ? p1 : p0, oacc[ct], 0, 0, 0);
            }
        } else {
            #pragma unroll
            for (int cb = 0; cb < 8; cb++)
                s = __builtin_amdgcn_mfma_f32_32x32x16_fp8_fp8(kf[cb], qf[cb], s, 0, 0, 0);
        }
        __builtin_amdgcn_s_setprio(0);
        float e[16];
        #pragma unroll
        for (int r = 0; r < 16; r++) e[r] = __builtin_amdgcn_exp2f(s[r]);
        #pragma unroll
        for (int r = 0; r < 8; r++) { La += e[r]; Lb2 += e[r + 8]; }
        const unsigned int A0 = pk_fp8x4(e[0],  e[1],  e[2],  e[3]);
        const unsigned int B0 = pk_fp8x4(e[4],  e[5],  e[6],  e[7]);
        const unsigned int A1 = pk_fp8x4(e[8],  e[9],  e[10], e[11]);
        const unsigned int B1 = pk_fp8x4(e[12], e[13], e[14], e[15]);
        u32x2 f0 = __builtin_amdgcn_permlane32_swap(A0, B0, false, false);
        u32x2 f1 = __builtin_amdgcn_permlane32_swap(A1, B1, false, false);
        p0 = mk64(f0[0], f0[1]);   // keys +0..15
        p1 = mk64(f1[0], f1[1]);   // keys +16..31
        #pragma unroll
        for (int j = 0; j < 8; j++) vf[j] = *(const long*)(vb8 + j * 512 + l * 8);
        // V reads must land before stage(t+2) overwrites this buffer
        asm volatile("s_waitcnt lgkmcnt(0)" ::: "memory");
    };

    // prologue: two tiles in flight, wait only the first (counted)
    stage(0, 0);
    stage(1, 1);
    asm volatile("s_waitcnt vmcnt(4)" ::: "memory");
    __builtin_amdgcn_s_barrier();
    __builtin_amdgcn_sched_barrier(0);

    compute(0, 0);
    __builtin_amdgcn_s_barrier();
    stage(2, 0);
    asm volatile("s_waitcnt vmcnt(4)" ::: "memory");
    __builtin_amdgcn_s_barrier();
    __builtin_amdgcn_sched_barrier(0);

    for (int t = 1; t < NT; t++) {
        compute(t, 1);
        __builtin_amdgcn_s_barrier();
        if (t + 2 < NT) {
            stage(t + 2, t & 1);
            asm volatile("s_waitcnt vmcnt(4)" ::: "memory");
        } else {
            asm volatile("s_waitcnt vmcnt(0)" ::: "memory");
        }
        __builtin_amdgcn_s_barrier();
        __builtin_amdgcn_sched_barrier(0);
    }
    // drain PV of the final tile
    __builtin_amdgcn_s_setprio(1);
    #pragma unroll
    for (int ct = 0; ct < 4; ct++) {
        oacc[ct] = __builtin_amdgcn_mfma_f32_32x32x16_fp8_fp8(vf[2*ct],   p0, oacc[ct], 0, 0, 0);
        oacc[ct] = __builtin_amdgcn_mfma_f32_32x32x16_fp8_fp8(vf[2*ct+1], p1, oacc[ct], 0, 0, 0);
    }
    __builtin_amdgcn_s_setprio(0);
    __syncthreads();

    // ---- combine 4 key-split partials per q-group (smem as f32 [4][128][33]) ----
    float* Ol = (float*)smem;
    const float Lh = La + Lb2;
    const float Lsum = Lh + __shfl_xor(Lh, 32, 64);

    for (int g = 0; g < 2; g++) {
        if (qi == g) {
            #pragma unroll
            for (int ct = 0; ct < 4; ct++)
                #pragma unroll
                for (int r = 0; r < 16; r++) {
                    const int c = 32 * ct + (r & 3) + 8 * (r >> 2) + 4 * h;
                    Ol[ks * 4224 + c * 33 + lo] = oacc[ct][r];
                }
            if (l < 32) Llds[ks][lo] = Lsum;
        }
        __syncthreads();
        {
            const int c = tid >> 2, qq = tid & 3;
            const size_t gbase = ((size_t)b * C_ + c) * N_ + q0 + g * 32 + qq * 8;
            float v[8];
            #pragma unroll
            for (int j = 0; j < 8; j++) {
                const int q = qq * 8 + j;
                const float ssum = Ol[c * 33 + q]        + Ol[4224  + c * 33 + q]
                                 + Ol[8448 + c * 33 + q] + Ol[12672 + c * 33 + q];
                const float Lq = Llds[0][q] + Llds[1][q] + Llds[2][q] + Llds[3][q];
                v[j] = ssum * __builtin_amdgcn_rcpf(Lq);
            }
            const f32x4 xlo = *(const f32x4*)&x1[gbase];
            const f32x4 xhi = *(const f32x4*)&x1[gbase + 4];
            *(f32x4*)&out[gbase]     = (f32x4){v[0]+xlo[0], v[1]+xlo[1], v[2]+xlo[2], v[3]+xlo[3]};
            *(f32x4*)&out[gbase + 4] = (f32x4){v[4]+xhi[0], v[5]+xhi[1], v[6]+xhi[2], v[7]+xhi[3]};
        }
        __syncthreads();
    }
}

extern "C" void kernel_launch(void* const* d_in, const int* in_sizes, int n_in,
                              void* d_out, int out_size, void* d_ws, size_t ws_size,
                              hipStream_t stream)
{
    const float* x1 = (const float*)d_in[0];
    const float* x2 = (const float*)d_in[1];
    const float* wq = (const float*)d_in[2];
    const float* bq = (const float*)d_in[3];
    const float* wk = (const float*)d_in[4];
    const float* bk = (const float*)d_in[5];
    const float* wv = (const float*)d_in[6];
    const float* bv = (const float*)d_in[7];
    float* out = (float*)d_out;

    unsigned short* Wf = (unsigned short*)d_ws;                    // 96 KB bf16 frags
    unsigned char* Qf = (unsigned char*)d_ws + 98304;              // 2 MB fp8 frags
    unsigned char* Kf = Qf + (size_t)B_ * 128 * 4096;              // 2 MB
    unsigned char* Vf = Kf + (size_t)B_ * 128 * 4096;              // 2 MB

    wcvt_kernel<<<24, 256, 0, stream>>>(wq, wk, wv, Wf);
    proj_kernel<<<512, 256, 0, stream>>>(x1, x2, bq, bk, bv, Wf, Qf, Kf, Vf);
    attn_kernel<<<256, 512, 0, stream>>>(Qf, Kf, Vf, x1, out);
}

// Round 6
// 50.709 us; speedup vs baseline: 1.0836x; 1.0836x over previous
//
#include <hip/hip_runtime.h>
#include <hip/hip_bf16.h>

typedef float  f32x4  __attribute__((ext_vector_type(4)));
typedef float  f32x16 __attribute__((ext_vector_type(16)));
typedef short  s16x8  __attribute__((ext_vector_type(8)));
typedef unsigned int   u32x2 __attribute__((ext_vector_type(2)));
typedef unsigned int   u32x4 __attribute__((ext_vector_type(4)));

#define B_ 4
#define C_ 128
#define N_ 4096
#define NT2 16           // 256-key supertiles
#define QSCALE 0.12751744f   // 1/sqrt(128) * log2(e)

typedef __attribute__((address_space(3))) unsigned int       lds_u32;
typedef __attribute__((address_space(1))) const unsigned int glb_u32;

// pack two f32 -> bf16x2 (round-half-up via +0x8000 + v_perm)
__device__ __forceinline__ unsigned int pkbf(float lo, float hi) {
    union { float f; unsigned int u; } a, b; a.f = lo; b.f = hi;
    return __builtin_amdgcn_perm(b.u + 0x8000u, a.u + 0x8000u, 0x07060302u);
}
// pack 4 f32 -> 4 fp8 e4m3 in one u32
__device__ __forceinline__ unsigned int pk_fp8x4(float a, float b, float c, float d) {
    int v = __builtin_amdgcn_cvt_pk_fp8_f32(a, b, 0, false);
    v = __builtin_amdgcn_cvt_pk_fp8_f32(c, d, v, true);
    return (unsigned int)v;
}
__device__ __forceinline__ s16x8 mk_frag(unsigned int a, unsigned int b,
                                         unsigned int c, unsigned int d) {
    union { u32x4 u; s16x8 v; } t; t.u = (u32x4){a, b, c, d}; return t.v;
}
__device__ __forceinline__ long mk64(unsigned int a, unsigned int b) {
    union { u32x2 u; long l; } t; t.u = (u32x2){a, b}; return t.l;
}
__device__ __forceinline__ f32x16 z16() {
    f32x16 v;
    #pragma unroll
    for (int r = 0; r < 16; r++) v[r] = 0.f;
    return v;
}
__device__ __forceinline__ void cp16(const unsigned char* g, unsigned char* l) {
    __builtin_amdgcn_global_load_lds((glb_u32*)g, (lds_u32*)l, 16, 0, 0);
}

// ---------------- W -> bf16 fragment-major (tiny, once) ----------------
__global__ __launch_bounds__(256) void wcvt_kernel(
    const float* __restrict__ wq, const float* __restrict__ wk,
    const float* __restrict__ wv, unsigned short* __restrict__ Wf)
{
    const int gid = blockIdx.x * 256 + threadIdx.x;   // 0..6143
    const int l = gid & 63, fid = gid >> 6;           // fid 0..95
    const int kc = fid & 7, ot = (fid >> 3) & 3, z = fid >> 5;
    const float* w = (z == 0) ? wq : (z == 1 ? wk : wv);
    const int o  = 32 * ot + (l & 31);
    const int c0 = 16 * kc + 8 * (l >> 5);
    const float* src = &w[o * C_ + c0];
    *(u32x4*)&Wf[fid * 512 + l * 8] = (u32x4){
        pkbf(src[0], src[1]), pkbf(src[2], src[3]),
        pkbf(src[4], src[5]), pkbf(src[6], src[7])};
}

// ---------------- projection: LDS-transposed X, bf16 MFMA, fp8 frag outputs ----
__global__ __launch_bounds__(256, 2) void proj_kernel(
    const float* __restrict__ x1, const float* __restrict__ x2,
    const float* __restrict__ bq, const float* __restrict__ bk,
    const float* __restrict__ bv,
    const unsigned short* __restrict__ Wf,
    unsigned char* __restrict__ Qf, unsigned char* __restrict__ Kf,
    unsigned char* __restrict__ Vf)
{
    __shared__ float Xs[2][C_ * 36];
    const int tid = threadIdx.x;
    const int ot  = tid >> 6;
    const int l = tid & 63, lo = l & 31, h = l >> 5;
    const int bid = blockIdx.x;
    const int b = bid & 3, tb = bid >> 2;
    const int n0 = tb * 32;

    { // coalesced f32x4 loads -> LDS [c][tok]
        const int q = tid & 7, c0 = tid >> 3;
        #pragma unroll
        for (int cc = 0; cc < 4; cc++) {
            const int c = c0 + 32 * cc;
            const size_t gof = ((size_t)b * C_ + c) * N_ + n0 + 4 * q;
            *(f32x4*)&Xs[0][c * 36 + 4 * q] = *(const f32x4*)&x1[gof];
            *(f32x4*)&Xs[1][c * 36 + 4 * q] = *(const f32x4*)&x2[gof];
        }
    }
    __syncthreads();

    auto ldW = [&](int z, int kc) -> s16x8 {
        return *(const s16x8*)&Wf[(((z * 4 + ot) * 8) + kc) * 512 + l * 8];
    };
    auto xfrag = [&](int z, int kc) -> s16x8 {
        const float* p = &Xs[z][(16 * kc + 8 * h) * 36 + lo];
        float f[8];
        #pragma unroll
        for (int i = 0; i < 8; i++) f[i] = p[i * 36];
        return mk_frag(pkbf(f[0], f[1]), pkbf(f[2], f[3]),
                       pkbf(f[4], f[5]), pkbf(f[6], f[7]));
    };

    f32x16 aq = z16(), ak = z16(), av = z16();
    s16x8 wqA = ldW(0, 0), wkA = ldW(1, 0), wvA = ldW(2, 0);
    s16x8 wqB, wkB, wvB;
    #pragma unroll
    for (int kc = 0; kc < 8; kc++) {
        if (kc & 1) {
            if (kc < 7) { wqA = ldW(0, kc + 1); wkA = ldW(1, kc + 1); wvA = ldW(2, kc + 1); }
            s16x8 f1 = xfrag(0, kc), f2 = xfrag(1, kc);
            aq = __builtin_amdgcn_mfma_f32_32x32x16_bf16(wqB, f1, aq, 0, 0, 0);
            ak = __builtin_amdgcn_mfma_f32_32x32x16_bf16(wkB, f2, ak, 0, 0, 0);
            av = __builtin_amdgcn_mfma_f32_32x32x16_bf16(f2, wvB, av, 0, 0, 0);
        } else {
            if (kc < 7) { wqB = ldW(0, kc + 1); wkB = ldW(1, kc + 1); wvB = ldW(2, kc + 1); }
            s16x8 f1 = xfrag(0, kc), f2 = xfrag(1, kc);
            aq = __builtin_amdgcn_mfma_f32_32x32x16_bf16(wqA, f1, aq, 0, 0, 0);
            ak = __builtin_amdgcn_mfma_f32_32x32x16_bf16(wkA, f2, ak, 0, 0, 0);
            av = __builtin_amdgcn_mfma_f32_32x32x16_bf16(f2, wvA, av, 0, 0, 0);
        }
    }

    const size_t fbase = (size_t)(b * 128 + tb) * 4096;
    auto slot_addr = [&](int rq) -> size_t {
        return fbase + (size_t)(2 * ot + (rq >> 1)) * 512 + (lo + 32 * (rq & 1)) * 8 + 4 * h;
    };
    #pragma unroll
    for (int rq = 0; rq < 4; rq++) {
        const int o0 = 32 * ot + 8 * rq + 4 * h;
        const f32x4 b4q = *(const f32x4*)&bq[o0];
        const f32x4 b4k = *(const f32x4*)&bk[o0];
        *(unsigned int*)&Qf[slot_addr(rq)] = pk_fp8x4(
            (aq[4*rq+0] + b4q[0]) * QSCALE, (aq[4*rq+1] + b4q[1]) * QSCALE,
            (aq[4*rq+2] + b4q[2]) * QSCALE, (aq[4*rq+3] + b4q[3]) * QSCALE);
        *(unsigned int*)&Kf[slot_addr(rq)] = pk_fp8x4(
            ak[4*rq+0] + b4k[0], ak[4*rq+1] + b4k[1],
            ak[4*rq+2] + b4k[2], ak[4*rq+3] + b4k[3]);
    }
    {
        const float bvv = bv[32 * ot + lo];
        #pragma unroll
        for (int rq = 0; rq < 4; rq++)
            *(unsigned int*)&Vf[slot_addr(rq)] = pk_fp8x4(
                av[4*rq+0] + bvv, av[4*rq+1] + bvv,
                av[4*rq+2] + bvv, av[4*rq+3] + bvv);
    }
}

// ---------------- attention: fp8, 16 waves (4/SIMD), 256-key supertiles ----
// 256 blocks x 1024 thr; wave w: qi = w&1 (32-q tile), ks = w>>1 (32-key slice of 256)
__global__ __launch_bounds__(1024, 1) void attn_kernel(
    const unsigned char* __restrict__ Qf,
    const unsigned char* __restrict__ Kf,
    const unsigned char* __restrict__ Vf,
    const float* __restrict__ x1,
    float* __restrict__ out)
{
    __shared__ __align__(16) unsigned char smem[2][65536]; // dbuf: K 32K + V 32K each
    __shared__ float Llds[8][32];

    const int tid = threadIdx.x;
    const int w  = tid >> 6;                  // 0..15
    const int qi = w & 1, ks = w >> 1;        // ks 0..7
    const int l = tid & 63, lo = l & 31, h = l >> 5;
    const int bid = blockIdx.x;
    const int xcd = bid & 7, slot = bid >> 3; // XCD-aware: batch b on XCDs {2b,2b+1}
    const int b  = xcd >> 1;
    const int qt = ((xcd & 1) << 5) | slot;   // 0..63
    const int q0 = qt * 64;

    const unsigned char* Kb = Kf + (size_t)b * 128 * 4096;
    const unsigned char* Vb = Vf + (size_t)b * 128 * 4096;

    long qf[8];
    {
        const unsigned char* qp = Qf + (size_t)(b * 128 + qt * 2 + qi) * 4096 + l * 8;
        #pragma unroll
        for (int cb = 0; cb < 8; cb++) qf[cb] = *(const long*)(qp + cb * 512);
    }

    f32x16 oacc[4];
    #pragma unroll
    for (int ct = 0; ct < 4; ct++) oacc[ct] = z16();
    float La = 0.f, Lb2 = 0.f;

    auto stage = [&](int t, int buf) {
        const int tp = (t + slot) & 15;        // staggered sweep (L2 de-sync)
        const unsigned char* Ks = Kb + (size_t)tp * 32768;
        const unsigned char* Vs = Vb + (size_t)tp * 32768;
        unsigned char* db = &smem[buf][0];
        cp16(Ks + (2*w)   * 1024 + l * 16, db + (2*w)   * 1024);
        cp16(Ks + (2*w+1) * 1024 + l * 16, db + (2*w+1) * 1024);
        cp16(Vs + (2*w)   * 1024 + l * 16, db + 32768 + (2*w)   * 1024);
        cp16(Vs + (2*w+1) * 1024 + l * 16, db + 32768 + (2*w+1) * 1024);
    };

    auto compute = [&](int buf) {
        const unsigned char* db  = &smem[buf][0];
        const unsigned char* kb8 = db + ks * 4096;
        f32x16 s = z16();
        #pragma unroll
        for (int cb = 0; cb < 8; cb++) {
            long kf = *(const long*)(kb8 + cb * 512 + l * 8);
            s = __builtin_amdgcn_mfma_f32_32x32x16_fp8_fp8(kf, qf[cb], s, 0, 0, 0);
        }
        float e[16];
        #pragma unroll
        for (int r = 0; r < 16; r++) e[r] = __builtin_amdgcn_exp2f(s[r]);
        #pragma unroll
        for (int r = 0; r < 8; r++) { La += e[r]; Lb2 += e[r + 8]; }
        const unsigned int A0 = pk_fp8x4(e[0],  e[1],  e[2],  e[3]);
        const unsigned int B0 = pk_fp8x4(e[4],  e[5],  e[6],  e[7]);
        const unsigned int A1 = pk_fp8x4(e[8],  e[9],  e[10], e[11]);
        const unsigned int B1 = pk_fp8x4(e[12], e[13], e[14], e[15]);
        u32x2 f0 = __builtin_amdgcn_permlane32_swap(A0, B0, false, false);
        u32x2 f1 = __builtin_amdgcn_permlane32_swap(A1, B1, false, false);
        const long p0 = mk64(f0[0], f0[1]);   // keys +0..15
        const long p1 = mk64(f1[0], f1[1]);   // keys +16..31
        const unsigned char* vb8 = db + 32768 + ks * 4096;
        #pragma unroll
        for (int ct = 0; ct < 4; ct++) {
            long v0 = *(const long*)(vb8 + (2*ct)   * 512 + l * 8);
            long v1 = *(const long*)(vb8 + (2*ct+1) * 512 + l * 8);
            oacc[ct] = __builtin_amdgcn_mfma_f32_32x32x16_fp8_fp8(v0, p0, oacc[ct], 0, 0, 0);
            oacc[ct] = __builtin_amdgcn_mfma_f32_32x32x16_fp8_fp8(v1, p1, oacc[ct], 0, 0, 0);
        }
    };

    // prologue: two supertiles in flight, wait only the first (counted vmcnt)
    stage(0, 0);
    stage(1, 1);
    asm volatile("s_waitcnt vmcnt(4)" ::: "memory");
    __builtin_amdgcn_s_barrier();
    __builtin_amdgcn_sched_barrier(0);

    for (int t = 0; t < NT2; t++) {
        compute(t & 1);
        __builtin_amdgcn_s_barrier();            // all waves done reading buf t&1
        if (t + 2 < NT2) {
            stage(t + 2, t & 1);
            asm volatile("s_waitcnt vmcnt(4)" ::: "memory");  // t+1's loads landed
        } else {
            asm volatile("s_waitcnt vmcnt(0)" ::: "memory");
        }
        __builtin_amdgcn_s_barrier();
        __builtin_amdgcn_sched_barrier(0);
    }
    __syncthreads();

    // ---- combine 8 key-split partials per q-group (smem as f32 [8][128][32]) ----
    float* Ol = (float*)&smem[0][0];
    const float Lh = La + Lb2;
    const float Lsum = Lh + __shfl_xor(Lh, 32, 64);

    for (int g = 0; g < 2; g++) {
        if (qi == g) {
            #pragma unroll
            for (int ct = 0; ct < 4; ct++)
                #pragma unroll
                for (int r = 0; r < 16; r++) {
                    const int c = 32 * ct + (r & 3) + 8 * (r >> 2) + 4 * h;
                    Ol[ks * 4096 + c * 32 + lo] = oacc[ct][r];
                }
            if (l < 32) Llds[ks][lo] = Lsum;
        }
        __syncthreads();
        {
            const int q = tid & 31, c0 = tid >> 5;   // c0 0..31
            float Lq = 0.f;
            #pragma unroll
            for (int s8 = 0; s8 < 8; s8++) Lq += Llds[s8][q];
            const float inv = __builtin_amdgcn_rcpf(Lq);
            #pragma unroll
            for (int j = 0; j < 4; j++) {
                const int c = c0 + 32 * j;
                float ssum = 0.f;
                #pragma unroll
                for (int s8 = 0; s8 < 8; s8++) ssum += Ol[s8 * 4096 + c * 32 + q];
                const size_t idx = ((size_t)b * C_ + c) * N_ + q0 + g * 32 + q;
                out[idx] = ssum * inv + x1[idx];
            }
        }
        __syncthreads();
    }
}

extern "C" void kernel_launch(void* const* d_in, const int* in_sizes, int n_in,
                              void* d_out, int out_size, void* d_ws, size_t ws_size,
                              hipStream_t stream)
{
    const float* x1 = (const float*)d_in[0];
    const float* x2 = (const float*)d_in[1];
    const float* wq = (const float*)d_in[2];
    const float* bq = (const float*)d_in[3];
    const float* wk = (const float*)d_in[4];
    const float* bk = (const float*)d_in[5];
    const float* wv = (const float*)d_in[6];
    const float* bv = (const float*)d_in[7];
    float* out = (float*)d_out;

    unsigned short* Wf = (unsigned short*)d_ws;                    // 96 KB bf16 frags
    unsigned char* Qf = (unsigned char*)d_ws + 98304;              // 2 MB fp8 frags
    unsigned char* Kf = Qf + (size_t)B_ * 128 * 4096;              // 2 MB
    unsigned char* Vf = Kf + (size_t)B_ * 128 * 4096;              // 2 MB

    wcvt_kernel<<<24, 256, 0, stream>>>(wq, wk, wv, Wf);
    proj_kernel<<<512, 256, 0, stream>>>(x1, x2, bq, bk, bv, Wf, Qf, Kf, Vf);
    attn_kernel<<<256, 1024, 0, stream>>>(Qf, Kf, Vf, x1, out);
}